// Round 1
// baseline (150.914 us; speedup 1.0000x reference)
//
#include <hip/hip_runtime.h>
#include <hip/hip_bf16.h>

#define BATCH 32
#define WW 900
#define CCH 256
#define MSTRIP 128
#define NCHUNK 128
#define PVAL 450

typedef __bf16 bf16x8 __attribute__((ext_vector_type(8)));
typedef float f32x4 __attribute__((ext_vector_type(4)));

// ---------------- norm pass 1: partial sums of squares ----------------
// grid = 256 blocks: which(2) x b(32) x seg(4); block = 256 threads (c)
// ws layout: sums[64][4][256] floats, then inv[64][256] at float offset 65536
__global__ void nc_norm_partial(const float* __restrict__ x1,
                                const float* __restrict__ x2,
                                float* __restrict__ sums) {
    int blk = blockIdx.x;
    int seg = blk & 3;
    int b = (blk >> 2) & 31;
    int which = blk >> 7;
    const float* x = which ? x2 : x1;
    int c = threadIdx.x;
    const float* p = x + ((size_t)b * WW + seg * 225) * CCH + c;
    float s = 0.f;
    #pragma unroll 8
    for (int w = 0; w < 225; ++w) {
        float v = p[(size_t)w * CCH];
        s = fmaf(v, v, s);
    }
    sums[(((which << 5) | b) * 4 + seg) * CCH + c] = s;
}

// ---------------- norm pass 2: inv = rsqrt(max(sum, eps)) ----------------
__global__ void nc_norm_finalize(float* __restrict__ ws) {
    int i = blockIdx.x * 256 + threadIdx.x;   // [0, 64*256)
    int c = i & 255;
    int wb = i >> 8;                          // which*32 + b
    const float* s = ws + (size_t)wb * 4 * CCH + c;
    float t = (s[0] + s[CCH]) + (s[2 * CCH] + s[3 * CCH]);
    ws[65536 + i] = rsqrtf(fmaxf(t, 1e-12f));
}

// Stage 128 rows x 256 ch of fp32, multiply by inv, cast bf16, XOR-swizzled LDS.
__device__ __forceinline__ void stage_tile(const float* __restrict__ src0,  // batch base
                                           const float* __restrict__ invv,  // 256 factors
                                           __bf16* __restrict__ dst,        // LDS 128*256
                                           int r0, int tid) {
    #pragma unroll 4
    for (int it = 0; it < 16; ++it) {
        int gidx = it * 256 + tid;
        int row = gidx >> 5;   // 0..127
        int g = gidx & 31;     // 16B granule within row
        int m = r0 + row;
        bf16x8 v;
        if (m < WW) {
            const float* s = src0 + (size_t)m * CCH + (g << 3);
            float4 f0 = *(const float4*)s;
            float4 f1 = *(const float4*)(s + 4);
            float4 i0 = *(const float4*)(invv + (g << 3));
            float4 i1 = *(const float4*)(invv + (g << 3) + 4);
            v[0] = (__bf16)(f0.x * i0.x);
            v[1] = (__bf16)(f0.y * i0.y);
            v[2] = (__bf16)(f0.z * i0.z);
            v[3] = (__bf16)(f0.w * i0.w);
            v[4] = (__bf16)(f1.x * i1.x);
            v[5] = (__bf16)(f1.y * i1.y);
            v[6] = (__bf16)(f1.z * i1.z);
            v[7] = (__bf16)(f1.w * i1.w);
        } else {
            #pragma unroll
            for (int e = 0; e < 8; ++e) v[e] = (__bf16)0.f;
        }
        // swizzle: granule g -> g ^ (row&7) breaks the stride-512B bank conflict
        *(bf16x8*)(dst + row * CCH + ((g ^ (row & 7)) << 3)) = v;
    }
}

// ---------------- main: per-batch strip GEMM + fused diagonal reduction ----------------
// grid = 256: b = blockIdx&31 (keeps a batch's strips on one XCD), strip = blockIdx>>5
__global__ __launch_bounds__(256, 1)
void nc_corr(const float* __restrict__ x1,
             const float* __restrict__ x2,
             const float* __restrict__ ws,
             float* __restrict__ out) {
    __shared__ __bf16 Abuf[MSTRIP * CCH];   // 64 KB
    __shared__ __bf16 Bbuf[NCHUNK * CCH];   // 64 KB
    __shared__ float partial[WW];           // 3.6 KB

    const int tid = threadIdx.x;
    const int b = blockIdx.x & 31;
    const int strip = blockIdx.x >> 5;
    const int m0 = strip * MSTRIP;

    const float* __restrict__ inv1 = ws + 65536 + b * CCH;
    const float* __restrict__ inv2 = ws + 65536 + (BATCH + b) * CCH;
    const float* __restrict__ x1b = x1 + (size_t)b * WW * CCH;
    const float* __restrict__ x2b = x2 + (size_t)b * WW * CCH;

    for (int i = tid; i < WW; i += 256) partial[i] = 0.f;

    stage_tile(x1b, inv1, Abuf, m0, tid);

    const int lane = tid & 63;
    const int wave = tid >> 6;
    const int wm = wave >> 1;      // wave row (64-row block)
    const int wn = wave & 1;       // wave col (64-col block)
    const int fr = lane & 15;      // fragment row (A row / B col within 16x16 tile)
    const int fq = lane >> 4;      // k-subgroup for A/B; row-group for C/D

    __syncthreads();   // A staged, partial zeroed

    for (int chunk = 0; chunk < 8; ++chunk) {
        const int n0 = chunk * NCHUNK;
        stage_tile(x2b, inv2, Bbuf, n0, tid);
        __syncthreads();

        f32x4 acc[4][4];
        #pragma unroll
        for (int mt = 0; mt < 4; ++mt)
            #pragma unroll
            for (int nt = 0; nt < 4; ++nt)
                acc[mt][nt] = (f32x4){0.f, 0.f, 0.f, 0.f};

        #pragma unroll
        for (int kk = 0; kk < 8; ++kk) {
            bf16x8 af[4], bfr[4];
            #pragma unroll
            for (int mt = 0; mt < 4; ++mt) {
                int row = wm * 64 + mt * 16 + fr;
                int gr = (kk * 4 + fq) ^ (row & 7);
                af[mt] = *(const bf16x8*)(&Abuf[row * CCH + (gr << 3)]);
            }
            #pragma unroll
            for (int nt = 0; nt < 4; ++nt) {
                int row = wn * 64 + nt * 16 + fr;
                int gr = (kk * 4 + fq) ^ (row & 7);
                bfr[nt] = *(const bf16x8*)(&Bbuf[row * CCH + (gr << 3)]);
            }
            #pragma unroll
            for (int mt = 0; mt < 4; ++mt)
                #pragma unroll
                for (int nt = 0; nt < 4; ++nt)
                    acc[mt][nt] = __builtin_amdgcn_mfma_f32_16x16x32_bf16(
                        af[mt], bfr[nt], acc[mt][nt], 0, 0, 0);
        }
        __syncthreads();   // everyone done reading Bbuf before next restage

        // Epilogue: G[m,i] -> out j = (m - i - 450) mod 900.
        // Tiles with equal (mt-nt) share m-i per (lane,reg): combine in regs first.
        const int base_mi = (m0 + wm * 64) - (n0 + wn * 64) + 4 * fq - fr - PVAL;
        #pragma unroll
        for (int d = -3; d <= 3; ++d) {
            f32x4 comb = (f32x4){0.f, 0.f, 0.f, 0.f};
            #pragma unroll
            for (int mt = 0; mt < 4; ++mt) {
                int nt = mt - d;
                if (nt >= 0 && nt < 4) comb += acc[mt][nt];
            }
            int j0 = base_mi + 16 * d;
            j0 %= WW;
            if (j0 < 0) j0 += WW;
            #pragma unroll
            for (int r = 0; r < 4; ++r) {
                int j = j0 + r;
                if (j >= WW) j -= WW;
                atomicAdd(&partial[j], comb[r]);
            }
        }
    }

    __syncthreads();
    for (int i = tid; i < WW; i += 256)
        atomicAdd(&out[(size_t)b * WW + i], partial[i]);
}

extern "C" void kernel_launch(void* const* d_in, const int* in_sizes, int n_in,
                              void* d_out, int out_size, void* d_ws, size_t ws_size,
                              hipStream_t stream) {
    const float* x1 = (const float*)d_in[0];
    const float* x2 = (const float*)d_in[1];
    float* out = (float*)d_out;
    float* ws = (float*)d_ws;   // needs 320 KB: 256 KB partial sums + 64 KB inv

    hipMemsetAsync(d_out, 0, (size_t)out_size * sizeof(float), stream);
    nc_norm_partial<<<256, 256, 0, stream>>>(x1, x2, ws);
    nc_norm_finalize<<<64, 256, 0, stream>>>(ws);
    nc_corr<<<256, 256, 0, stream>>>(x1, x2, ws, out);
}